// Round 5
// baseline (40.906 us; speedup 1.0000x reference)
//
#include <hip/hip_runtime.h>
#include <hip/hip_bf16.h>
#include <cstddef>

typedef __attribute__((ext_vector_type(8))) short bf16x8;
typedef __attribute__((ext_vector_type(4))) float f32x4;
typedef __attribute__((ext_vector_type(2))) unsigned int u32x2;
typedef __attribute__((ext_vector_type(4))) unsigned int u32x4;

#define NB 4
#define CIN 64
#define COUT 64
#define HH 128
#define WW 128
#define TAPS 9
#define KCH 144          // 16 ch * 9 taps, no pad
#define KTOT 576
#define STRD 76          // dwords per sCor row: 304 B, 16B-aligned, gcd(76,32)=4
#define BUFD (64 * STRD)

__device__ __forceinline__ unsigned short f2bf(float f) {
    union { float f; unsigned u; } v; v.f = f;
    unsigned u = v.u + 0x7FFFu + ((v.u >> 16) & 1u);   // RNE
    return (unsigned short)(u >> 16);
}

// wB[o][kk], kk = chunk*144 + tap*16 + cl ; zrow = 192 zero floats
__global__ void prep_weight(const float* __restrict__ w, unsigned short* __restrict__ wB,
                            float* __restrict__ zrow) {
    int idx = blockIdx.x * blockDim.x + threadIdx.x;
    if (idx < 192) zrow[idx] = 0.f;
    if (idx >= COUT * KTOT) return;
    int o = idx / KTOT;
    int kk = idx - o * KTOT;
    int chunk = kk / KCH;
    int kl = kk - chunk * KCH;
    int tap = kl >> 4;
    int cl = kl & 15;
    wB[idx] = f2bf(w[(o * CIN + chunk * 16 + cl) * TAPS + tap]);
}

__launch_bounds__(256, 4)
__global__ void pac_conv(const float* __restrict__ x, const float* __restrict__ Kp,
                         const unsigned short* __restrict__ wB,
                         const float* __restrict__ bias,
                         const float* __restrict__ zrow1,   // zrow+1 (covers idx -1..190)
                         float* __restrict__ out) {
    __shared__ __align__(16) unsigned int sCor[2][BUFD];   // 38912 B -> 4 blocks/CU

    const int blk = blockIdx.x;               // 1024
    const int w0 = (blk & 1) * 64;
    const int h  = (blk >> 1) & (HH - 1);
    const int n  = blk >> 8;
    const int t    = threadIdx.x;
    const int lane = t & 63;
    const int wv   = __builtin_amdgcn_readfirstlane(t >> 6);

    // per-pixel adapting kernel -> registers (lane = pixel)
    float kreg[TAPS];
    float ks = 0.f;
    const float* kp = Kp + ((size_t)n * TAPS * HH + h) * WW + w0 + lane;
    #pragma unroll
    for (int tap = 0; tap < TAPS; ++tap) {
        kreg[tap] = kp[(size_t)tap * HH * WW];
        ks += kreg[tap];
    }
    const float inv = 1.0f / ks;

    // w-edge handling: base biased by -1 float; unsigned byte offsets
    const bool mL = (w0 == 0) && (lane == 0);
    const bool mR = (w0 != 0) && (lane == 63);
    const unsigned voffL = (mL ? 1u : (unsigned)lane) * 4u;
    const unsigned voffC = ((unsigned)lane + 1u) * 4u;
    const unsigned voffR = (mR ? 64u : (unsigned)lane + 2u) * 4u;

    const int l15 = lane & 15;
    const int g   = lane >> 4;
    const int gg  = g & 1;
    const bool gok = (g < 2);
    const float bval = bias[wv * 16 + l15];

    f32x4 acc[4];
    #pragma unroll
    for (int i = 0; i < 4; ++i) acc[i] = (f32x4){0.f, 0.f, 0.f, 0.f};

    // MFMA over one staged chunk (4 full K32 steps + masked K16 tail)
    auto mfma_chunk = [&](int c) {
        const unsigned int* src = &sCor[c & 1][0];
        const unsigned short* wrow = wB + (size_t)(wv * 16 + l15) * KTOT + c * KCH + g * 8;
        #pragma unroll
        for (int step = 0; step < 4; ++step) {
            bf16x8 bfrag = *reinterpret_cast<const bf16x8*>(wrow + step * 32);
            #pragma unroll
            for (int pt = 0; pt < 4; ++pt) {
                u32x4 a = *reinterpret_cast<const u32x4*>(
                    &src[(pt * 16 + l15) * STRD + step * 16 + g * 4]);
                acc[pt] = __builtin_amdgcn_mfma_f32_16x16x32_bf16(
                    __builtin_bit_cast(bf16x8, a), bfrag, acc[pt], 0, 0, 0);
            }
        }
        // tail: k 128..143 real for g<2, zero for g>=2
        const unsigned short* wtail =
            wB + (size_t)(wv * 16 + l15) * KTOT + c * KCH + 128 + gg * 8;
        u32x4 bu = *reinterpret_cast<const u32x4*>(wtail);
        if (!gok) bu = (u32x4){0u, 0u, 0u, 0u};
        bf16x8 btail = __builtin_bit_cast(bf16x8, bu);
        #pragma unroll
        for (int pt = 0; pt < 4; ++pt) {
            u32x4 a = *reinterpret_cast<const u32x4*>(
                &src[(pt * 16 + l15) * STRD + 64 + gg * 4]);
            if (!gok) a = (u32x4){0u, 0u, 0u, 0u};
            acc[pt] = __builtin_amdgcn_mfma_f32_16x16x32_bf16(
                __builtin_bit_cast(bf16x8, a), btail, acc[pt], 0, 0, 0);
        }
    };

    #pragma unroll
    for (int chunk = 0; chunk < 4; ++chunk) {
        // ---- stage-compute chunk (loads issued first, VALU pack) ----
        u32x2 cor[TAPS];
        {
            const int c0 = chunk * 16 + wv * 4;
            const float* xb = x + (size_t)(n * CIN + c0) * (HH * WW) + w0 - 1;
            float prev[TAPS];
            #pragma unroll
            for (int j = 0; j < 4; ++j) {
                float xv[TAPS];
                #pragma unroll
                for (int k = 0; k < 3; ++k) {
                    const int hh2 = h + k - 1;
                    const float* p = ((unsigned)hh2 < (unsigned)HH)
                        ? (xb + (size_t)j * (HH * WW) + (size_t)hh2 * WW)
                        : (zrow1 - 1);
                    float vL = *(const float*)((const char*)p + voffL);
                    float vC = *(const float*)((const char*)p + voffC);
                    float vR = *(const float*)((const char*)p + voffR);
                    xv[k * 3 + 0] = mL ? 0.f : vL;
                    xv[k * 3 + 1] = vC;
                    xv[k * 3 + 2] = mR ? 0.f : vR;
                }
                float s = 0.f;
                #pragma unroll
                for (int tap = 0; tap < TAPS; ++tap) s = fmaf(xv[tap], kreg[tap], s);
                const float d = s * inv;
                if (j & 1) {
                    #pragma unroll
                    for (int tap = 0; tap < TAPS; ++tap) {
                        float cc = fmaf(kreg[tap], xv[tap] - d, d);
                        union { __hip_bfloat162 h2; unsigned int u; } pk;
                        pk.h2 = __float22bfloat162_rn(make_float2(prev[tap], cc));
                        cor[tap][j >> 1] = pk.u;
                    }
                } else {
                    #pragma unroll
                    for (int tap = 0; tap < TAPS; ++tap)
                        prev[tap] = fmaf(kreg[tap], xv[tap] - d, d);
                }
            }
        }

        // ---- MFMA previous chunk (overlaps the staging loads above) ----
        if (chunk > 0) mfma_chunk(chunk - 1);

        // ---- write this chunk to the other buffer; one barrier ----
        unsigned int* dst = &sCor[chunk & 1][lane * STRD + wv * 2];
        #pragma unroll
        for (int tap = 0; tap < TAPS; ++tap)
            *reinterpret_cast<u32x2*>(dst + tap * 8) = cor[tap];
        __syncthreads();
    }
    mfma_chunk(3);

    // epilogue: direct float4 stores
    const int o = wv * 16 + l15;
    float* op = out + (((size_t)n * COUT + o) * HH + h) * WW + w0 + g * 4;
    #pragma unroll
    for (int pt = 0; pt < 4; ++pt) {
        f32x4 v = acc[pt];
        #pragma unroll
        for (int r = 0; r < 4; ++r) v[r] += bval;
        *reinterpret_cast<f32x4*>(op + pt * 16) = v;
    }
}

extern "C" void kernel_launch(void* const* d_in, const int* in_sizes, int n_in,
                              void* d_out, int out_size, void* d_ws, size_t ws_size,
                              hipStream_t stream) {
    const float* x    = (const float*)d_in[0];
    const float* Kp   = (const float*)d_in[1];
    const float* wgt  = (const float*)d_in[2];
    const float* bias = (const float*)d_in[3];
    float* out = (float*)d_out;
    unsigned short* wB = (unsigned short*)d_ws;          // 64*576*2 = 73728 B
    float* zrow = (float*)((char*)d_ws + 73728);         // 192 zero floats

    prep_weight<<<(COUT * KTOT + 255) / 256, 256, 0, stream>>>(wgt, wB, zrow);

    pac_conv<<<NB * HH * 2, 256, 0, stream>>>(x, Kp, wB, bias, zrow + 1, out);
}

// Round 6
// 29.033 us; speedup vs baseline: 1.4089x; 1.4089x over previous
//
#include <hip/hip_runtime.h>
#include <hip/hip_bf16.h>
#include <cstddef>

typedef __attribute__((ext_vector_type(8))) short bf16x8;
typedef __attribute__((ext_vector_type(4))) float f32x4;
typedef __attribute__((ext_vector_type(2))) unsigned int u32x2;

#define NB 4
#define CIN 64
#define COUT 64
#define HH 128
#define WW 128
#define TAPS 9
#define KCH 160      // padded K per chunk (144 real + 16 zero)
#define KTOT 640
#define STRD 82      // sCor row stride in dwords (41 qwords: odd -> conflict-free b64)

__device__ __forceinline__ unsigned short f2bf(float f) {
    union { float f; unsigned u; } v; v.f = f;
    unsigned u = v.u + 0x7FFFu + ((v.u >> 16) & 1u);   // RNE
    return (unsigned short)(u >> 16);
}

// wB[o][kk], kk = chunk*160 + tap*16 + cl (zero-pad kl 144..159); zrow = 192 zero floats
__global__ void prep_weight(const float* __restrict__ w, unsigned short* __restrict__ wB,
                            float* __restrict__ zrow) {
    int idx = blockIdx.x * blockDim.x + threadIdx.x;
    if (idx < 192) zrow[idx] = 0.f;
    if (idx >= COUT * KTOT) return;
    int o = idx / KTOT;
    int kk = idx - o * KTOT;
    int chunk = kk / KCH;
    int kl = kk - chunk * KCH;
    unsigned short v = 0;
    if (kl < 16 * TAPS) {
        int tap = kl >> 4;
        int cl = kl & 15;
        v = f2bf(w[(o * CIN + chunk * 16 + cl) * TAPS + tap]);
    }
    wB[idx] = v;
}

__launch_bounds__(256)
__global__ void pac_conv(const float* __restrict__ x, const float* __restrict__ Kp,
                         const unsigned short* __restrict__ wB,
                         const float* __restrict__ bias,
                         const float* __restrict__ zrow1,   // zrow+1 (covers idx -1..190)
                         float* __restrict__ out) {
    __shared__ unsigned int sCor[64][STRD];   // 20992 B

    // XCD-chunked bijective swizzle: 1024 blocks, 8 XCDs, 128 per XCD.
    // Each XCD gets one n and 64 adjacent h -> x slice ~2.2 MB, L2-resident.
    const int blk0 = blockIdx.x;
    const int blk  = ((blk0 & 7) << 7) | (blk0 >> 3);

    const int w0 = (blk & 1) * 64;
    const int h  = (blk >> 1) & (HH - 1);
    const int n  = blk >> 8;
    const int t    = threadIdx.x;
    const int lane = t & 63;
    const int wv   = __builtin_amdgcn_readfirstlane(t >> 6);

    // per-pixel adapting kernel -> registers (lane = pixel)
    float kreg[TAPS];
    float ks = 0.f;
    const float* kp = Kp + ((size_t)n * TAPS * HH + h) * WW + w0 + lane;
    #pragma unroll
    for (int tap = 0; tap < TAPS; ++tap) {
        kreg[tap] = kp[(size_t)tap * HH * WW];
        ks += kreg[tap];
    }
    const float inv = 1.0f / ks;

    // zero the K-pad dwords (kl 144..159 -> dw 72..79)
    for (int i = t; i < 64 * 8; i += 256) sCor[i >> 3][72 + (i & 7)] = 0u;

    // w-edge handling: base biased by -1 float; unsigned byte offsets
    const bool mL = (w0 == 0) && (lane == 0);
    const bool mR = (w0 != 0) && (lane == 63);
    const unsigned voffL = (mL ? 1u : (unsigned)lane) * 4u;        // tap l=0
    const unsigned voffC = ((unsigned)lane + 1u) * 4u;             // tap l=1
    const unsigned voffR = (mR ? 64u : (unsigned)lane + 2u) * 4u;  // tap l=2

    const int l15 = lane & 15;
    const int g   = lane >> 4;
    const float bval = bias[wv * 16 + l15];

    f32x4 acc[4];
    #pragma unroll
    for (int i = 0; i < 4; ++i) acc[i] = (f32x4){0.f, 0.f, 0.f, 0.f};

    for (int chunk = 0; chunk < 4; ++chunk) {
        const int c0 = chunk * 16 + wv * 4;               // wave-uniform
        const float* xb = x + (size_t)(n * CIN + c0) * (HH * WW) + w0 - 1;  // -1 bias

        // ---- issue ALL 36 loads of this chunk before any consumption (MLP=36) ----
        float xv[4][TAPS];
        #pragma unroll
        for (int j = 0; j < 4; ++j) {
            #pragma unroll
            for (int k = 0; k < 3; ++k) {
                const int hh2 = h + k - 1;
                const float* p = ((unsigned)hh2 < (unsigned)HH)
                    ? (xb + (size_t)j * (HH * WW) + (size_t)hh2 * WW)
                    : (zrow1 - 1);
                float vL = *(const float*)((const char*)p + voffL);
                float vC = *(const float*)((const char*)p + voffC);
                float vR = *(const float*)((const char*)p + voffR);
                xv[j][k * 3 + 0] = mL ? 0.f : vL;
                xv[j][k * 3 + 1] = vC;
                xv[j][k * 3 + 2] = mR ? 0.f : vR;
            }
        }

        // ---- dominate + corrected + bf16 pack ----
        float dom[4];
        #pragma unroll
        for (int j = 0; j < 4; ++j) {
            float s = 0.f;
            #pragma unroll
            for (int tap = 0; tap < TAPS; ++tap) s = fmaf(xv[j][tap], kreg[tap], s);
            dom[j] = s * inv;
        }
        u32x2 cor[TAPS];
        #pragma unroll
        for (int tap = 0; tap < TAPS; ++tap) {
            float c0f = fmaf(kreg[tap], xv[0][tap] - dom[0], dom[0]);
            float c1f = fmaf(kreg[tap], xv[1][tap] - dom[1], dom[1]);
            float c2f = fmaf(kreg[tap], xv[2][tap] - dom[2], dom[2]);
            float c3f = fmaf(kreg[tap], xv[3][tap] - dom[3], dom[3]);
            union { __hip_bfloat162 h2; unsigned int u; } a, b;
            a.h2 = __float22bfloat162_rn(make_float2(c0f, c1f));
            b.h2 = __float22bfloat162_rn(make_float2(c2f, c3f));
            cor[tap] = (u32x2){a.u, b.u};
        }

        if (chunk) __syncthreads();           // previous MFMA readers done
        #pragma unroll
        for (int tap = 0; tap < TAPS; ++tap)
            *reinterpret_cast<u32x2*>(&sCor[lane][tap * 8 + wv * 2]) = cor[tap];
        __syncthreads();

        // ---- MFMA: wave owns 16 outputs x 64 px ----
        const unsigned short* wrow = wB + (size_t)(wv * 16 + l15) * KTOT + chunk * KCH + g * 8;
        #pragma unroll
        for (int step = 0; step < 5; ++step) {
            bf16x8 bfrag = *reinterpret_cast<const bf16x8*>(wrow + step * 32);
            #pragma unroll
            for (int pt = 0; pt < 4; ++pt) {
                const unsigned int* ap = &sCor[pt * 16 + l15][step * 16 + g * 4];
                u32x2 alo = *reinterpret_cast<const u32x2*>(ap);
                u32x2 ahi = *reinterpret_cast<const u32x2*>(ap + 2);
                union { u32x2 p[2]; bf16x8 f; } af;
                af.p[0] = alo; af.p[1] = ahi;
                acc[pt] = __builtin_amdgcn_mfma_f32_16x16x32_bf16(af.f, bfrag, acc[pt], 0, 0, 0);
            }
        }
    }

    // epilogue: direct float4 stores (D rows = 4 consecutive px per thread)
    const int o = wv * 16 + l15;
    float* op = out + (((size_t)n * COUT + o) * HH + h) * WW + w0 + g * 4;
    #pragma unroll
    for (int pt = 0; pt < 4; ++pt) {
        f32x4 v = acc[pt];
        #pragma unroll
        for (int r = 0; r < 4; ++r) v[r] += bval;
        *reinterpret_cast<f32x4*>(op + pt * 16) = v;
    }
}

extern "C" void kernel_launch(void* const* d_in, const int* in_sizes, int n_in,
                              void* d_out, int out_size, void* d_ws, size_t ws_size,
                              hipStream_t stream) {
    const float* x    = (const float*)d_in[0];
    const float* Kp   = (const float*)d_in[1];
    const float* wgt  = (const float*)d_in[2];
    const float* bias = (const float*)d_in[3];
    float* out = (float*)d_out;
    unsigned short* wB = (unsigned short*)d_ws;              // 81920 B
    float* zrow = (float*)((char*)d_ws + 81920);             // 192 zero floats

    prep_weight<<<(COUT * KTOT + 255) / 256, 256, 0, stream>>>(wgt, wB, zrow);

    pac_conv<<<NB * HH * (WW / 64), 256, 0, stream>>>(x, Kp, wB, bias, zrow + 1, out);
}